// Round 8
// baseline (184.950 us; speedup 1.0000x reference)
//
#include <hip/hip_runtime.h>
#include <stdint.h>

// Problem constants
#define B_   2
#define S_   2048
#define D_   768
#define H_   12
#define DH_  64
#define N3_  2304   // 3*D
#define M_   4096   // B*S

typedef __attribute__((ext_vector_type(8))) short    bf16x8;
typedef __attribute__((ext_vector_type(4))) float    f32x4;
typedef __attribute__((ext_vector_type(4))) int      i32x4;
typedef __attribute__((ext_vector_type(4))) unsigned short u16x4;
typedef _Float16 f16x4 __attribute__((ext_vector_type(4)));
typedef __fp16   h16x2 __attribute__((ext_vector_type(2)));   // cvt_pkrtz result type

// fold 1/sqrt(dh) * log2(e) into K at write time -> scores exit MFMA in exp2 domain
#define KSCALE 0.18033688011112042f

__device__ inline unsigned short f2bf(float f) {
    union { float f; unsigned u; } v; v.f = f;
    unsigned r = v.u + 0x7FFFu + ((v.u >> 16) & 1u);   // RNE
    return (unsigned short)(r >> 16);
}

// async 16B global -> LDS (DMA; LDS dest = wave-uniform base + lane*16)
__device__ inline void async_copy16(const void* g, void* l) {
    __builtin_amdgcn_global_load_lds((const __attribute__((address_space(1))) void*)g,
                                     (__attribute__((address_space(3))) void*)l, 16, 0, 0);
}

// ---------------------------------------------------------------------------
// Prep: fp32 -> bf16 elementwise (vectorized x4)
__global__ void cvt_bf16(const float* __restrict__ in, unsigned short* __restrict__ out, int n4) {
    int i = blockIdx.x * blockDim.x + threadIdx.x;
    if (i >= n4) return;
    f32x4 v = *(const f32x4*)(in + (size_t)i * 4);
    u16x4 o;
    o.x = f2bf(v.x); o.y = f2bf(v.y); o.z = f2bf(v.z); o.w = f2bf(v.w);
    *(u16x4*)(out + (size_t)i * 4) = o;
}

// Prep: tiled transpose fp32 [R][C] -> bf16 [C][R]; R,C multiples of 32.
__global__ void transpose_bf16(const float* __restrict__ in, unsigned short* __restrict__ out,
                               int R, int C) {
    __shared__ unsigned short t[32][33];
    int c0 = blockIdx.x * 32, r0 = blockIdx.y * 32;
    int tx = threadIdx.x, ty = threadIdx.y;
#pragma unroll
    for (int j = 0; j < 4; j++)
        t[ty + j * 8][tx] = f2bf(in[(size_t)(r0 + ty + j * 8) * C + c0 + tx]);
    __syncthreads();
#pragma unroll
    for (int j = 0; j < 4; j++)
        out[(size_t)(c0 + ty + j * 8) * R + r0 + tx] = t[tx][ty + j * 8];
}

// V [bh][s][64] f16 -> Vt [bh][64][s] f16.  64x64 tiles, coalesced both sides.
__global__ void vtrans(const unsigned short* __restrict__ V, unsigned short* __restrict__ Vt) {
    __shared__ unsigned short t[64 * 65];
    const int bid = blockIdx.x;
    const int bh  = bid >> 5;
    const int s0  = (bid & 31) * 64;
    const int tid = threadIdx.x;
    const unsigned short* src = V  + (size_t)bh * S_ * DH_ + (size_t)s0 * DH_;
    unsigned short*       dst = Vt + (size_t)bh * DH_ * S_ + s0;
#pragma unroll
    for (int p = 0; p < 2; p++) {
        int c = p * 256 + tid;          // 0..511
        int s = c >> 3, dc = c & 7;
        i32x4 v = *(const i32x4*)&src[s * 64 + dc * 8];
        const unsigned short* e = (const unsigned short*)&v;
#pragma unroll
        for (int j = 0; j < 8; j++) t[(dc * 8 + j) * 65 + s] = e[j];
    }
    __syncthreads();
#pragma unroll
    for (int p = 0; p < 2; p++) {
        int c = p * 256 + tid;
        int d = c >> 3, sc = c & 7;
        unsigned short tmp[8];
#pragma unroll
        for (int j = 0; j < 8; j++) tmp[j] = t[d * 65 + sc * 8 + j];
        *(i32x4*)&dst[(size_t)d * S_ + sc * 8] = *(const i32x4*)tmp;
    }
}

// ---------------------------------------------------------------------------
// bf16 MFMA GEMM: C[M][N] = A[M][K] * Bt[N][K]^T + bias
// m97-style: global_load_lds width-16 staging, unpadded stride-32 LDS,
// 2-barrier K-loop. 128x128 tile, BK=32, 256 threads (4 waves 2x2).
// MODE 0: scatter into Q/K natural [bh][s][dh] bf16 (K scaled by KSCALE),
//         V natural [bh][s][dh] as FP16 into Vnat (PV pipeline runs fp16).
// MODE 1: fp32 C row-major to Cout.
template <int MODE>
__global__ __launch_bounds__(256) void gemm_bf16(
    const unsigned short* __restrict__ A,
    const unsigned short* __restrict__ Bt,
    const float* __restrict__ bias,
    void* __restrict__ Cout,
    unsigned short* __restrict__ Vnat,
    int M, int N, int K)
{
    __shared__ __align__(16) short Al[128 * 32];
    __shared__ __align__(16) short Bl[128 * 32];

    const int tid  = threadIdx.x;
    const int w    = tid >> 6;
    const int lane = tid & 63;
    const int r    = lane & 15;
    const int quad = lane >> 4;
    const int m0   = blockIdx.y * 128;
    const int n0   = blockIdx.x * 128;
    const int wm   = (w & 1) * 64;
    const int wn   = (w >> 1) * 64;

    f32x4 acc[4][4];
#pragma unroll
    for (int i = 0; i < 4; i++)
#pragma unroll
        for (int j = 0; j < 4; j++) acc[i][j] = f32x4{0.f, 0.f, 0.f, 0.f};

    const int c0 = tid, c1 = tid + 256;
    const size_t ga0 = (size_t)(m0 + (c0 >> 2)) * K + (c0 & 3) * 8;
    const size_t ga1 = (size_t)(m0 + (c1 >> 2)) * K + (c1 & 3) * 8;
    const size_t gb0 = (size_t)(n0 + (c0 >> 2)) * K + (c0 & 3) * 8;
    const size_t gb1 = (size_t)(n0 + (c1 >> 2)) * K + (c1 & 3) * 8;
    short* lA0 = &Al[(0 * 256 + w * 64) * 8];   // wave-uniform bases
    short* lA1 = &Al[(1 * 256 + w * 64) * 8];
    short* lB0 = &Bl[(0 * 256 + w * 64) * 8];
    short* lB1 = &Bl[(1 * 256 + w * 64) * 8];

    for (int k0 = 0; k0 < K; k0 += 32) {
        __syncthreads();
        async_copy16(A  + ga0 + k0, lA0);
        async_copy16(A  + ga1 + k0, lA1);
        async_copy16(Bt + gb0 + k0, lB0);
        async_copy16(Bt + gb1 + k0, lB1);
        __syncthreads();

        bf16x8 af[4], bf[4];
#pragma unroll
        for (int mi = 0; mi < 4; mi++)
            af[mi] = *(const bf16x8*)&Al[(wm + mi * 16 + r) * 32 + quad * 8];
#pragma unroll
        for (int ni = 0; ni < 4; ni++)
            bf[ni] = *(const bf16x8*)&Bl[(wn + ni * 16 + r) * 32 + quad * 8];
#pragma unroll
        for (int mi = 0; mi < 4; mi++)
#pragma unroll
            for (int ni = 0; ni < 4; ni++)
                acc[mi][ni] = __builtin_amdgcn_mfma_f32_16x16x32_bf16(
                    af[mi], bf[ni], acc[mi][ni], 0, 0, 0);
    }

    // Epilogue. C/D layout: col = lane&15 (+16*ni), row = quad*4 + reg (+16*mi)
    if (MODE == 0) {
        unsigned short* Q = (unsigned short*)Cout;   // Q,K consecutive
        const size_t one = (size_t)B_ * H_ * S_ * DH_;
#pragma unroll
        for (int ni = 0; ni < 4; ni++) {
            int col  = n0 + wn + ni * 16 + r;        // 0..2303
            float bv = bias[col];
            int part = col / 768;                    // 0=q 1=k 2=v
            int cc   = col - part * 768;
            int h    = cc >> 6;
            int d    = cc & 63;
            float scl = (part == 1) ? KSCALE : 1.0f;
            unsigned short* dst = (part == 2) ? Vnat : (Q + (size_t)part * one);
#pragma unroll
            for (int mi = 0; mi < 4; mi++) {
#pragma unroll
                for (int i = 0; i < 4; i++) {
                    int row = m0 + wm + mi * 16 + quad * 4 + i;  // = b*S + s
                    int b   = row >> 11;
                    int s   = row & 2047;
                    float v = (acc[mi][ni][i] + bv) * scl;
                    unsigned short bits;
                    if (part == 2) {                 // V -> fp16 (PV runs f16)
                        union { _Float16 h; unsigned short s; } cv;
                        cv.h = (_Float16)v;
                        bits = cv.s;
                    } else {
                        bits = f2bf(v);
                    }
                    dst[(((size_t)(b * H_ + h)) * S_ + s) * DH_ + d] = bits;
                }
            }
        }
    } else {
        float* Cf = (float*)Cout;
#pragma unroll
        for (int ni = 0; ni < 4; ni++) {
            int col  = n0 + wn + ni * 16 + r;
            float bv = bias[col];
#pragma unroll
            for (int mi = 0; mi < 4; mi++) {
#pragma unroll
                for (int i = 0; i < 4; i++) {
                    int row = m0 + wm + mi * 16 + quad * 4 + i;
                    Cf[(size_t)row * N + col] = acc[mi][ni][i] + bv;
                }
            }
        }
    }
}

// ---------------------------------------------------------------------------
// Flash attention v5: S^T scheme — no P LDS round-trip.
//   S^T = K·Q^T via mfma_16x16x32_bf16 (A=K rows, B=Q rows): C-layout gives
//   lane r reg i = S[key=kb*16+quad*4+i][q=r], which IS the A-operand layout
//   of mfma_16x16x16f16 (m=r, k=quad*4+j). exp2 -> cvt_pkrtz f16 -> PV.
//   l = P·ones via an extra constant-B MFMA: lands in the SAME layout as O
//   (q=quad*4+i) from the SAME truncated P -> consistent normalization.
// Block = 128 q-rows, 4 waves x 32 q (2 q-tiles/wave; K/V frags amortized 2x).
// Grid = 24*16 = 384. LDS 16 KB (Kl+Vl only).
// Q,K: bf16 [B*H][S][64] (K pre-scaled). Vt: FP16 [B*H][64][S].
__global__ __launch_bounds__(256) void attn_kernel(
    const unsigned short* __restrict__ Q,
    const unsigned short* __restrict__ K,
    const unsigned short* __restrict__ Vt,
    unsigned short* __restrict__ Out)
{
    __shared__ __align__(16) short Kl[64 * 64];      // [key][dh], chunk^=(row&7)
    __shared__ __align__(16) short Vl[64 * 64];      // [dh][key], chunk^=(row&7)

    const int tid  = threadIdx.x;
    const int w    = tid >> 6;
    const int lane = tid & 63;
    const int r    = lane & 15;
    const int quad = lane >> 4;
    const int xk   = r & 7;
    const int bid  = blockIdx.x;
    const int bh   = bid % 24;            // head-major -> L2 locality
    const int qb   = bid / 24;            // 0..15
    const int b    = bh / H_;
    const int h    = bh - b * H_;
    const size_t baseQK = (size_t)bh * S_ * DH_;
    const size_t baseV  = (size_t)bh * DH_ * S_;
    const int q0   = qb * 128;

    // Q fragments (B-operand of S^T: B[k=quad*8+j][n=r] = Q[q=r][d]) — natural rows
    bf16x8 qf[2][2];
#pragma unroll
    for (int qt = 0; qt < 2; qt++) {
        const unsigned short* qp =
            Q + baseQK + (size_t)(q0 + w * 32 + qt * 16 + r) * DH_ + quad * 8;
        qf[qt][0] = *(const bf16x8*)(qp);
        qf[qt][1] = *(const bf16x8*)(qp + 32);
    }

    f32x4 o[2][4];
    f32x4 lacc[2];
#pragma unroll
    for (int qt = 0; qt < 2; qt++) {
        lacc[qt] = f32x4{0.f, 0.f, 0.f, 0.f};
#pragma unroll
        for (int nb = 0; nb < 4; nb++) o[qt][nb] = f32x4{0.f, 0.f, 0.f, 0.f};
    }

    const f16x4 ONES = {(_Float16)1.f, (_Float16)1.f, (_Float16)1.f, (_Float16)1.f};

    // staging: chunk c = p*256 + tid (p=0,1); srow = c>>3 (0..63), schk = c&7
    const int srw = tid >> 3, schk = tid & 7;
    const unsigned short* kg = K  + baseQK + tid * 8;                       // p1: +2048
    const unsigned short* vg = Vt + baseV + (size_t)srw * S_ + schk * 8;    // p1: +32*S_
    const int lb = srw * 64 + (schk ^ (srw & 7)) * 8;                       // p1: +2048

    i32x4 kreg[2], vreg[2];
    kreg[0] = *(const i32x4*)(kg);
    kreg[1] = *(const i32x4*)(kg + 2048);
    vreg[0] = *(const i32x4*)(vg);
    vreg[1] = *(const i32x4*)(vg + 32 * S_);

    for (int kt = 0; kt < 32; kt++) {
        __syncthreads();
        *(i32x4*)&Kl[lb]        = kreg[0];
        *(i32x4*)&Kl[lb + 2048] = kreg[1];
        *(i32x4*)&Vl[lb]        = vreg[0];
        *(i32x4*)&Vl[lb + 2048] = vreg[1];
        __syncthreads();

        if (kt != 31) {
            const unsigned short* kn = kg + (kt + 1) * 4096;
            const unsigned short* vn = vg + (kt + 1) * 64;
            kreg[0] = *(const i32x4*)(kn);
            kreg[1] = *(const i32x4*)(kn + 2048);
            vreg[0] = *(const i32x4*)(vn);
            vreg[1] = *(const i32x4*)(vn + 32 * S_);
        }

        // S^T = K Q^T  (exp2 domain; KSCALE folded into K)
        f32x4 sa[2][4];
#pragma unroll
        for (int qt = 0; qt < 2; qt++)
#pragma unroll
            for (int kb = 0; kb < 4; kb++) sa[qt][kb] = f32x4{0.f, 0.f, 0.f, 0.f};
#pragma unroll
        for (int t = 0; t < 2; t++)
#pragma unroll
            for (int kb = 0; kb < 4; kb++) {
                bf16x8 kf = *(const bf16x8*)&Kl[(kb * 16 + r) * 64 + ((t * 4 + quad) ^ xk) * 8];
#pragma unroll
                for (int qt = 0; qt < 2; qt++)
                    sa[qt][kb] = __builtin_amdgcn_mfma_f32_16x16x32_bf16(
                        kf, qf[qt][t], sa[qt][kb], 0, 0, 0);
            }

        // p = exp2(s) -> f16 A-frags (layout already matches; cvt_pkrtz = RTZ)
        f16x4 pf[2][4];
#pragma unroll
        for (int qt = 0; qt < 2; qt++)
#pragma unroll
            for (int kb = 0; kb < 4; kb++) {
                float p0 = __builtin_amdgcn_exp2f(sa[qt][kb][0]);
                float p1 = __builtin_amdgcn_exp2f(sa[qt][kb][1]);
                float p2 = __builtin_amdgcn_exp2f(sa[qt][kb][2]);
                float p3 = __builtin_amdgcn_exp2f(sa[qt][kb][3]);
                union { f16x4 v; h16x2 h[2]; } u;
                u.h[0] = __builtin_amdgcn_cvt_pkrtz(p0, p1);
                u.h[1] = __builtin_amdgcn_cvt_pkrtz(p2, p3);
                pf[qt][kb] = u.v;
            }

        // O += P V  and  l += P 1   (fp16 MFMA, K=16 per kb)
#pragma unroll
        for (int kb = 0; kb < 4; kb++) {
#pragma unroll
            for (int nb = 0; nb < 4; nb++) {
                f16x4 vf = *(const f16x4*)&Vl[(nb * 16 + r) * 64 +
                                              ((kb * 2 + (quad >> 1)) ^ xk) * 8 + (quad & 1) * 4];
#pragma unroll
                for (int qt = 0; qt < 2; qt++)
                    o[qt][nb] = __builtin_amdgcn_mfma_f32_16x16x16f16(
                        pf[qt][kb], vf, o[qt][nb], 0, 0, 0);
            }
#pragma unroll
            for (int qt = 0; qt < 2; qt++)
                lacc[qt] = __builtin_amdgcn_mfma_f32_16x16x16f16(
                    pf[qt][kb], ONES, lacc[qt], 0, 0, 0);
        }
    }

    // epilogue: l is in the same layout as O (q = quad*4+i) — no shuffles
#pragma unroll
    for (int qt = 0; qt < 2; qt++)
#pragma unroll
        for (int i = 0; i < 4; i++) {
            float inv = 1.0f / lacc[qt][i];
            int s = q0 + w * 32 + qt * 16 + quad * 4 + i;
            size_t ob = ((size_t)b * S_ + s) * D_ + h * DH_;
#pragma unroll
            for (int nb = 0; nb < 4; nb++)
                Out[ob + nb * 16 + r] = f2bf(o[qt][nb][i] * inv);
        }
}

// ---------------------------------------------------------------------------
extern "C" void kernel_launch(void* const* d_in, const int* in_sizes, int n_in,
                              void* d_out, int out_size, void* d_ws, size_t ws_size,
                              hipStream_t stream) {
    const float* x     = (const float*)d_in[0];
    const float* w_in  = (const float*)d_in[1];
    const float* b_in  = (const float*)d_in[2];
    const float* w_out = (const float*)d_in[3];
    const float* b_out = (const float*)d_in[4];
    float* out = (float*)d_out;
    char* ws = (char*)d_ws;

    // workspace layout (bytes), total 36.2 MB:
    //   [0,        6291456)  xb (x bf16)     -> reused as attn output after gemm1
    //   [6291456,  9830400)  winT
    //   [9830400, 11010048)  woutT
    //   [11010048,29884416)  QKV: Q, K natural bf16; slot 3 = Vt (fp16)
    //   [29884416,36175872)  tmpV (V natural fp16; dead after vtrans)
    unsigned short* xb    = (unsigned short*)(ws);
    unsigned short* winT  = (unsigned short*)(ws + 6291456);
    unsigned short* woutT = (unsigned short*)(ws + 9830400);
    unsigned short* QKV   = (unsigned short*)(ws + 11010048);
    unsigned short* tmpV  = (unsigned short*)(ws + 29884416);

    const size_t one = (size_t)B_ * H_ * S_ * DH_;
    unsigned short* Vtbuf  = QKV + 2 * one;
    unsigned short* attnO  = xb;    // xb dead after gemm1

    cvt_bf16<<<3072, 256, 0, stream>>>(x, xb, (M_ * D_) / 4);
    transpose_bf16<<<dim3(N3_ / 32, D_ / 32), dim3(32, 8), 0, stream>>>(w_in, winT, D_, N3_);
    transpose_bf16<<<dim3(D_ / 32, D_ / 32), dim3(32, 8), 0, stream>>>(w_out, woutT, D_, D_);

    gemm_bf16<0><<<dim3(N3_ / 128, M_ / 128), 256, 0, stream>>>(
        xb, winT, b_in, (void*)QKV, tmpV, M_, N3_, D_);

    vtrans<<<24 * 32, 256, 0, stream>>>(tmpV, Vtbuf);

    attn_kernel<<<24 * (S_ / 128), 256, 0, stream>>>(
        QKV, QKV + one, Vtbuf, attnO);

    gemm_bf16<1><<<dim3(D_ / 128, M_ / 128), 256, 0, stream>>>(
        attnO, woutT, b_out, (void*)out, nullptr, M_, D_, D_);
}

// Round 9
// 179.187 us; speedup vs baseline: 1.0322x; 1.0322x over previous
//
#include <hip/hip_runtime.h>
#include <stdint.h>

// Problem constants
#define B_   2
#define S_   2048
#define D_   768
#define H_   12
#define DH_  64
#define N3_  2304   // 3*D
#define M_   4096   // B*S

typedef __attribute__((ext_vector_type(8))) short    bf16x8;
typedef __attribute__((ext_vector_type(4))) float    f32x4;
typedef __attribute__((ext_vector_type(4))) int      i32x4;
typedef __attribute__((ext_vector_type(4))) unsigned short u16x4;
typedef _Float16 f16x4 __attribute__((ext_vector_type(4)));
typedef __fp16   h16x2 __attribute__((ext_vector_type(2)));   // cvt_pkrtz result type

// fold 1/sqrt(dh) * log2(e) into K at write time -> scores exit MFMA in exp2 domain
#define KSCALE 0.18033688011112042f

__device__ inline unsigned short f2bf(float f) {
    union { float f; unsigned u; } v; v.f = f;
    unsigned r = v.u + 0x7FFFu + ((v.u >> 16) & 1u);   // RNE
    return (unsigned short)(r >> 16);
}

// async 16B global -> LDS (DMA; LDS dest = wave-uniform base + lane*16)
__device__ inline void async_copy16(const void* g, void* l) {
    __builtin_amdgcn_global_load_lds((const __attribute__((address_space(1))) void*)g,
                                     (__attribute__((address_space(3))) void*)l, 16, 0, 0);
}

// ---------------------------------------------------------------------------
// Prep: fp32 -> bf16 elementwise (vectorized x4)
__global__ void cvt_bf16(const float* __restrict__ in, unsigned short* __restrict__ out, int n4) {
    int i = blockIdx.x * blockDim.x + threadIdx.x;
    if (i >= n4) return;
    f32x4 v = *(const f32x4*)(in + (size_t)i * 4);
    u16x4 o;
    o.x = f2bf(v.x); o.y = f2bf(v.y); o.z = f2bf(v.z); o.w = f2bf(v.w);
    *(u16x4*)(out + (size_t)i * 4) = o;
}

// Prep: tiled transpose fp32 [R][C] -> bf16 [C][R]; R,C multiples of 32.
__global__ void transpose_bf16(const float* __restrict__ in, unsigned short* __restrict__ out,
                               int R, int C) {
    __shared__ unsigned short t[32][33];
    int c0 = blockIdx.x * 32, r0 = blockIdx.y * 32;
    int tx = threadIdx.x, ty = threadIdx.y;
#pragma unroll
    for (int j = 0; j < 4; j++)
        t[ty + j * 8][tx] = f2bf(in[(size_t)(r0 + ty + j * 8) * C + c0 + tx]);
    __syncthreads();
#pragma unroll
    for (int j = 0; j < 4; j++)
        out[(size_t)(c0 + ty + j * 8) * R + r0 + tx] = t[tx][ty + j * 8];
}

// V [bh][s][64] f16 -> Vt [bh][64][s] f16.  64x64 tiles, coalesced both sides.
__global__ void vtrans(const unsigned short* __restrict__ V, unsigned short* __restrict__ Vt) {
    __shared__ unsigned short t[64 * 65];
    const int bid = blockIdx.x;
    const int bh  = bid >> 5;
    const int s0  = (bid & 31) * 64;
    const int tid = threadIdx.x;
    const unsigned short* src = V  + (size_t)bh * S_ * DH_ + (size_t)s0 * DH_;
    unsigned short*       dst = Vt + (size_t)bh * DH_ * S_ + s0;
#pragma unroll
    for (int p = 0; p < 2; p++) {
        int c = p * 256 + tid;          // 0..511
        int s = c >> 3, dc = c & 7;
        i32x4 v = *(const i32x4*)&src[s * 64 + dc * 8];
        const unsigned short* e = (const unsigned short*)&v;
#pragma unroll
        for (int j = 0; j < 8; j++) t[(dc * 8 + j) * 65 + s] = e[j];
    }
    __syncthreads();
#pragma unroll
    for (int p = 0; p < 2; p++) {
        int c = p * 256 + tid;
        int d = c >> 3, sc = c & 7;
        unsigned short tmp[8];
#pragma unroll
        for (int j = 0; j < 8; j++) tmp[j] = t[d * 65 + sc * 8 + j];
        *(i32x4*)&dst[(size_t)d * S_ + sc * 8] = *(const i32x4*)tmp;
    }
}

// ---------------------------------------------------------------------------
// bf16 MFMA GEMM: C[M][N] = A[M][K] * Bt[N][K]^T + bias
// m97-style: global_load_lds width-16 staging, unpadded stride-32 LDS,
// 2-barrier K-loop. 128x128 tile, BK=32, 256 threads (4 waves 2x2).
// MODE 0: scatter into Q/K natural [bh][s][dh] bf16 (K scaled by KSCALE),
//         V natural [bh][s][dh] as FP16 into Vnat (PV pipeline runs fp16).
// MODE 1: fp32 C row-major to Cout.
template <int MODE>
__global__ __launch_bounds__(256) void gemm_bf16(
    const unsigned short* __restrict__ A,
    const unsigned short* __restrict__ Bt,
    const float* __restrict__ bias,
    void* __restrict__ Cout,
    unsigned short* __restrict__ Vnat,
    int M, int N, int K)
{
    __shared__ __align__(16) short Al[128 * 32];
    __shared__ __align__(16) short Bl[128 * 32];

    const int tid  = threadIdx.x;
    const int w    = tid >> 6;
    const int lane = tid & 63;
    const int r    = lane & 15;
    const int quad = lane >> 4;
    const int m0   = blockIdx.y * 128;
    const int n0   = blockIdx.x * 128;
    const int wm   = (w & 1) * 64;
    const int wn   = (w >> 1) * 64;

    f32x4 acc[4][4];
#pragma unroll
    for (int i = 0; i < 4; i++)
#pragma unroll
        for (int j = 0; j < 4; j++) acc[i][j] = f32x4{0.f, 0.f, 0.f, 0.f};

    const int c0 = tid, c1 = tid + 256;
    const size_t ga0 = (size_t)(m0 + (c0 >> 2)) * K + (c0 & 3) * 8;
    const size_t ga1 = (size_t)(m0 + (c1 >> 2)) * K + (c1 & 3) * 8;
    const size_t gb0 = (size_t)(n0 + (c0 >> 2)) * K + (c0 & 3) * 8;
    const size_t gb1 = (size_t)(n0 + (c1 >> 2)) * K + (c1 & 3) * 8;
    short* lA0 = &Al[(0 * 256 + w * 64) * 8];   // wave-uniform bases
    short* lA1 = &Al[(1 * 256 + w * 64) * 8];
    short* lB0 = &Bl[(0 * 256 + w * 64) * 8];
    short* lB1 = &Bl[(1 * 256 + w * 64) * 8];

    for (int k0 = 0; k0 < K; k0 += 32) {
        __syncthreads();
        async_copy16(A  + ga0 + k0, lA0);
        async_copy16(A  + ga1 + k0, lA1);
        async_copy16(Bt + gb0 + k0, lB0);
        async_copy16(Bt + gb1 + k0, lB1);
        __syncthreads();

        bf16x8 af[4], bf[4];
#pragma unroll
        for (int mi = 0; mi < 4; mi++)
            af[mi] = *(const bf16x8*)&Al[(wm + mi * 16 + r) * 32 + quad * 8];
#pragma unroll
        for (int ni = 0; ni < 4; ni++)
            bf[ni] = *(const bf16x8*)&Bl[(wn + ni * 16 + r) * 32 + quad * 8];
#pragma unroll
        for (int mi = 0; mi < 4; mi++)
#pragma unroll
            for (int ni = 0; ni < 4; ni++)
                acc[mi][ni] = __builtin_amdgcn_mfma_f32_16x16x32_bf16(
                    af[mi], bf[ni], acc[mi][ni], 0, 0, 0);
    }

    // Epilogue. C/D layout: col = lane&15 (+16*ni), row = quad*4 + reg (+16*mi)
    if (MODE == 0) {
        unsigned short* Q = (unsigned short*)Cout;   // Q,K consecutive
        const size_t one = (size_t)B_ * H_ * S_ * DH_;
#pragma unroll
        for (int ni = 0; ni < 4; ni++) {
            int col  = n0 + wn + ni * 16 + r;        // 0..2303
            float bv = bias[col];
            int part = col / 768;                    // 0=q 1=k 2=v
            int cc   = col - part * 768;
            int h    = cc >> 6;
            int d    = cc & 63;
            float scl = (part == 1) ? KSCALE : 1.0f;
            unsigned short* dst = (part == 2) ? Vnat : (Q + (size_t)part * one);
#pragma unroll
            for (int mi = 0; mi < 4; mi++) {
#pragma unroll
                for (int i = 0; i < 4; i++) {
                    int row = m0 + wm + mi * 16 + quad * 4 + i;  // = b*S + s
                    int b   = row >> 11;
                    int s   = row & 2047;
                    float v = (acc[mi][ni][i] + bv) * scl;
                    unsigned short bits;
                    if (part == 2) {                 // V -> fp16 (PV runs f16)
                        union { _Float16 h; unsigned short s; } cv;
                        cv.h = (_Float16)v;
                        bits = cv.s;
                    } else {
                        bits = f2bf(v);
                    }
                    dst[(((size_t)(b * H_ + h)) * S_ + s) * DH_ + d] = bits;
                }
            }
        }
    } else {
        float* Cf = (float*)Cout;
#pragma unroll
        for (int ni = 0; ni < 4; ni++) {
            int col  = n0 + wn + ni * 16 + r;
            float bv = bias[col];
#pragma unroll
            for (int mi = 0; mi < 4; mi++) {
#pragma unroll
                for (int i = 0; i < 4; i++) {
                    int row = m0 + wm + mi * 16 + quad * 4 + i;
                    Cf[(size_t)row * N + col] = acc[mi][ni][i] + bv;
                }
            }
        }
    }
}

// ---------------------------------------------------------------------------
// Flash attention v6: S^T scheme + split-K (x2).
// No max-subtraction softmax combines linearly across key ranges:
//   O = (O0 + O1) / (l0 + l1).  Each block handles 16 of 32 kt-iters.
// Grid = 24 * 16 * 2 = 768 = exactly 3 blocks/CU (balanced, 12 waves/CU).
// Partials: Onum f16 [half][bh][s][64], l f32 [half][bh][s].
// Q,K: bf16 [B*H][S][64] (K pre-scaled). Vt: FP16 [B*H][64][S].
__global__ __launch_bounds__(256) void attn_kernel(
    const unsigned short* __restrict__ Q,
    const unsigned short* __restrict__ K,
    const unsigned short* __restrict__ Vt,
    unsigned short* __restrict__ On0,
    unsigned short* __restrict__ On1,
    float* __restrict__ lbuf)
{
    __shared__ __align__(16) short Kl[64 * 64];      // [key][dh], chunk^=(row&7)
    __shared__ __align__(16) short Vl[64 * 64];      // [dh][key], chunk^=(row&7)

    const int tid  = threadIdx.x;
    const int w    = tid >> 6;
    const int lane = tid & 63;
    const int r    = lane & 15;
    const int quad = lane >> 4;
    const int xk   = r & 7;
    const int bid  = blockIdx.x;
    const int bh   = bid % 24;            // head-major -> L2 locality
    const int t2   = bid / 24;            // 0..31
    const int qb   = t2 & 15;
    const int half = t2 >> 4;
    const size_t baseQK = (size_t)bh * S_ * DH_;
    const size_t baseV  = (size_t)bh * DH_ * S_;
    const int q0   = qb * 128;
    const int kt0  = half * 16;

    // Q fragments (B-operand of S^T: B[k=quad*8+j][n=r] = Q[q=r][d])
    bf16x8 qf[2][2];
#pragma unroll
    for (int qt = 0; qt < 2; qt++) {
        const unsigned short* qp =
            Q + baseQK + (size_t)(q0 + w * 32 + qt * 16 + r) * DH_ + quad * 8;
        qf[qt][0] = *(const bf16x8*)(qp);
        qf[qt][1] = *(const bf16x8*)(qp + 32);
    }

    f32x4 o[2][4];
    f32x4 lacc[2];
#pragma unroll
    for (int qt = 0; qt < 2; qt++) {
        lacc[qt] = f32x4{0.f, 0.f, 0.f, 0.f};
#pragma unroll
        for (int nb = 0; nb < 4; nb++) o[qt][nb] = f32x4{0.f, 0.f, 0.f, 0.f};
    }

    const f16x4 ONES = {(_Float16)1.f, (_Float16)1.f, (_Float16)1.f, (_Float16)1.f};

    // staging: chunk c = p*256 + tid (p=0,1); srow = c>>3 (0..63), schk = c&7
    const int srw = tid >> 3, schk = tid & 7;
    const unsigned short* kg = K  + baseQK + (size_t)kt0 * 4096 + tid * 8;
    const unsigned short* vg = Vt + baseV + (size_t)kt0 * 64 + (size_t)srw * S_ + schk * 8;
    const int lb = srw * 64 + (schk ^ (srw & 7)) * 8;

    i32x4 kreg[2], vreg[2];
    kreg[0] = *(const i32x4*)(kg);
    kreg[1] = *(const i32x4*)(kg + 2048);
    vreg[0] = *(const i32x4*)(vg);
    vreg[1] = *(const i32x4*)(vg + 32 * S_);

    for (int it = 0; it < 16; it++) {
        __syncthreads();
        *(i32x4*)&Kl[lb]        = kreg[0];
        *(i32x4*)&Kl[lb + 2048] = kreg[1];
        *(i32x4*)&Vl[lb]        = vreg[0];
        *(i32x4*)&Vl[lb + 2048] = vreg[1];
        __syncthreads();

        if (it != 15) {
            const unsigned short* kn = kg + (it + 1) * 4096;
            const unsigned short* vn = vg + (it + 1) * 64;
            kreg[0] = *(const i32x4*)(kn);
            kreg[1] = *(const i32x4*)(kn + 2048);
            vreg[0] = *(const i32x4*)(vn);
            vreg[1] = *(const i32x4*)(vn + 32 * S_);
        }

        // S^T = K Q^T  (exp2 domain; KSCALE folded into K)
        f32x4 sa[2][4];
#pragma unroll
        for (int qt = 0; qt < 2; qt++)
#pragma unroll
            for (int kb = 0; kb < 4; kb++) sa[qt][kb] = f32x4{0.f, 0.f, 0.f, 0.f};
#pragma unroll
        for (int t = 0; t < 2; t++)
#pragma unroll
            for (int kb = 0; kb < 4; kb++) {
                bf16x8 kf = *(const bf16x8*)&Kl[(kb * 16 + r) * 64 + ((t * 4 + quad) ^ xk) * 8];
#pragma unroll
                for (int qt = 0; qt < 2; qt++)
                    sa[qt][kb] = __builtin_amdgcn_mfma_f32_16x16x32_bf16(
                        kf, qf[qt][t], sa[qt][kb], 0, 0, 0);
            }

        // p = exp2(s) -> f16 A-frags (layout already matches; cvt_pkrtz = RTZ)
        f16x4 pf[2][4];
#pragma unroll
        for (int qt = 0; qt < 2; qt++)
#pragma unroll
            for (int kb = 0; kb < 4; kb++) {
                float p0 = __builtin_amdgcn_exp2f(sa[qt][kb][0]);
                float p1 = __builtin_amdgcn_exp2f(sa[qt][kb][1]);
                float p2 = __builtin_amdgcn_exp2f(sa[qt][kb][2]);
                float p3 = __builtin_amdgcn_exp2f(sa[qt][kb][3]);
                union { f16x4 v; h16x2 h[2]; } u;
                u.h[0] = __builtin_amdgcn_cvt_pkrtz(p0, p1);
                u.h[1] = __builtin_amdgcn_cvt_pkrtz(p2, p3);
                pf[qt][kb] = u.v;
            }

        // O += P V  and  l += P 1   (fp16 MFMA, K=16 per kb)
#pragma unroll
        for (int kb = 0; kb < 4; kb++) {
#pragma unroll
            for (int nb = 0; nb < 4; nb++) {
                f16x4 vf = *(const f16x4*)&Vl[(nb * 16 + r) * 64 +
                                              ((kb * 2 + (quad >> 1)) ^ xk) * 8 + (quad & 1) * 4];
#pragma unroll
                for (int qt = 0; qt < 2; qt++)
                    o[qt][nb] = __builtin_amdgcn_mfma_f32_16x16x16f16(
                        pf[qt][kb], vf, o[qt][nb], 0, 0, 0);
            }
#pragma unroll
            for (int qt = 0; qt < 2; qt++)
                lacc[qt] = __builtin_amdgcn_mfma_f32_16x16x16f16(
                    pf[qt][kb], ONES, lacc[qt], 0, 0, 0);
        }
    }

    // epilogue: store UN-normalized partials (f16) + l (f32)
    unsigned short* Ob = half ? On1 : On0;
#pragma unroll
    for (int qt = 0; qt < 2; qt++)
#pragma unroll
        for (int i = 0; i < 4; i++) {
            int s = q0 + w * 32 + qt * 16 + quad * 4 + i;
            size_t row = (size_t)bh * S_ + s;
            if (r == 0) lbuf[half * (24 * S_) + row] = lacc[qt][i];
#pragma unroll
            for (int nb = 0; nb < 4; nb++) {
                union { _Float16 h; unsigned short u; } cv;
                cv.h = (_Float16)o[qt][nb][i];
                Ob[row * 64 + nb * 16 + r] = cv.u;
            }
        }
}

// Combine split-K partials: out = (O0+O1)/(l0+l1), bf16 [B][S][D] heads merged.
// 393216 threads x 8 outputs each; fully coalesced 16B loads/stores.
__global__ void combine_attn(const unsigned short* __restrict__ On0,
                             const unsigned short* __restrict__ On1,
                             const float* __restrict__ lbuf,
                             unsigned short* __restrict__ Out)
{
    int g   = blockIdx.x * 256 + threadIdx.x;   // 0 .. 393215
    int hd8 = g % 96;                           // 12 heads * 8 chunks
    int bs  = g / 96;                           // b*2048 + s
    int h   = hd8 >> 3;
    int d8  = (hd8 & 7) * 8;
    size_t row = ((size_t)((bs >> 11) * H_ + h)) * S_ + (bs & 2047);
    float inv = 1.0f / (lbuf[row] + lbuf[24 * S_ + row]);
    i32x4 a = *(const i32x4*)&On0[row * 64 + d8];
    i32x4 c = *(const i32x4*)&On1[row * 64 + d8];
    const _Float16* fa = (const _Float16*)&a;
    const _Float16* fc = (const _Float16*)&c;
    unsigned short tmp[8];
#pragma unroll
    for (int j = 0; j < 8; j++)
        tmp[j] = f2bf(((float)fa[j] + (float)fc[j]) * inv);
    *(i32x4*)&Out[(size_t)bs * D_ + h * 64 + d8] = *(const i32x4*)tmp;
}

// ---------------------------------------------------------------------------
extern "C" void kernel_launch(void* const* d_in, const int* in_sizes, int n_in,
                              void* d_out, int out_size, void* d_ws, size_t ws_size,
                              hipStream_t stream) {
    const float* x     = (const float*)d_in[0];
    const float* w_in  = (const float*)d_in[1];
    const float* b_in  = (const float*)d_in[2];
    const float* w_out = (const float*)d_in[3];
    const float* b_out = (const float*)d_in[4];
    float* out = (float*)d_out;
    char* ws = (char*)d_ws;

    // workspace layout (bytes), total 36.2 MB (same proven footprint):
    //   [0,        6291456)  xb (x bf16)        -> reused as Onum half0 (f16) by attn
    //   [6291456,  9830400)  winT               -> reused as lbuf (f32, 393KB) by attn
    //   [9830400, 11010048)  woutT              (live until gemm2)
    //   [11010048,17301504)  Q  (bf16)          -> reused as attn output (bf16) by combine
    //   [17301504,23592960)  K  (bf16, scaled)
    //   [23592960,29884416)  Vt (fp16)
    //   [29884416,36175872)  tmpV (V natural)   -> reused as Onum half1 (f16) by attn
    unsigned short* xb    = (unsigned short*)(ws);
    unsigned short* winT  = (unsigned short*)(ws + 6291456);
    unsigned short* woutT = (unsigned short*)(ws + 9830400);
    unsigned short* QKV   = (unsigned short*)(ws + 11010048);
    unsigned short* tmpV  = (unsigned short*)(ws + 29884416);

    const size_t one = (size_t)B_ * H_ * S_ * DH_;
    unsigned short* Vtbuf = QKV + 2 * one;
    unsigned short* On0   = xb;                       // dead after gemm1
    unsigned short* On1   = tmpV;                     // dead after vtrans
    float*          lbuf  = (float*)winT;             // dead after gemm1
    unsigned short* attnO = QKV;                      // Q slot, dead after attn

    cvt_bf16<<<3072, 256, 0, stream>>>(x, xb, (M_ * D_) / 4);
    transpose_bf16<<<dim3(N3_ / 32, D_ / 32), dim3(32, 8), 0, stream>>>(w_in, winT, D_, N3_);
    transpose_bf16<<<dim3(D_ / 32, D_ / 32), dim3(32, 8), 0, stream>>>(w_out, woutT, D_, D_);

    gemm_bf16<0><<<dim3(N3_ / 128, M_ / 128), 256, 0, stream>>>(
        xb, winT, b_in, (void*)QKV, tmpV, M_, N3_, D_);

    vtrans<<<24 * 32, 256, 0, stream>>>(tmpV, Vtbuf);

    attn_kernel<<<24 * 16 * 2, 256, 0, stream>>>(
        QKV, QKV + one, Vtbuf, On0, On1, lbuf);

    combine_attn<<<1536, 256, 0, stream>>>(On0, On1, lbuf, attnO);

    gemm_bf16<1><<<dim3(D_ / 128, M_ / 128), 256, 0, stream>>>(
        attnO, woutT, b_out, (void*)out, nullptr, M_, D_, D_);
}

// Round 10
// 167.105 us; speedup vs baseline: 1.1068x; 1.0723x over previous
//
#include <hip/hip_runtime.h>
#include <stdint.h>

// Problem constants
#define B_   2
#define S_   2048
#define D_   768
#define H_   12
#define DH_  64
#define N3_  2304   // 3*D
#define M_   4096   // B*S

typedef __attribute__((ext_vector_type(8))) short    bf16x8;
typedef __attribute__((ext_vector_type(4))) float    f32x4;
typedef __attribute__((ext_vector_type(4))) int      i32x4;
typedef __attribute__((ext_vector_type(4))) unsigned short u16x4;
typedef _Float16 f16x4 __attribute__((ext_vector_type(4)));
typedef __fp16   h16x2 __attribute__((ext_vector_type(2)));   // cvt_pkrtz result type

// fold 1/sqrt(dh) * log2(e) into K at write time -> scores exit MFMA in exp2 domain
#define KSCALE 0.18033688011112042f

__device__ inline unsigned short f2bf(float f) {
    union { float f; unsigned u; } v; v.f = f;
    unsigned r = v.u + 0x7FFFu + ((v.u >> 16) & 1u);   // RNE
    return (unsigned short)(r >> 16);
}

// async 16B global -> LDS (DMA; LDS dest = wave-uniform base + lane*16)
__device__ inline void async_copy16(const void* g, void* l) {
    __builtin_amdgcn_global_load_lds((const __attribute__((address_space(1))) void*)g,
                                     (__attribute__((address_space(3))) void*)l, 16, 0, 0);
}

// ---------------------------------------------------------------------------
// Prep: fp32 -> bf16 elementwise (vectorized x4)
__global__ void cvt_bf16(const float* __restrict__ in, unsigned short* __restrict__ out, int n4) {
    int i = blockIdx.x * blockDim.x + threadIdx.x;
    if (i >= n4) return;
    f32x4 v = *(const f32x4*)(in + (size_t)i * 4);
    u16x4 o;
    o.x = f2bf(v.x); o.y = f2bf(v.y); o.z = f2bf(v.z); o.w = f2bf(v.w);
    *(u16x4*)(out + (size_t)i * 4) = o;
}

// Prep: tiled transpose fp32 [R][C] -> bf16 [C][R]; R,C multiples of 32.
__global__ void transpose_bf16(const float* __restrict__ in, unsigned short* __restrict__ out,
                               int R, int C) {
    __shared__ unsigned short t[32][33];
    int c0 = blockIdx.x * 32, r0 = blockIdx.y * 32;
    int tx = threadIdx.x, ty = threadIdx.y;
#pragma unroll
    for (int j = 0; j < 4; j++)
        t[ty + j * 8][tx] = f2bf(in[(size_t)(r0 + ty + j * 8) * C + c0 + tx]);
    __syncthreads();
#pragma unroll
    for (int j = 0; j < 4; j++)
        out[(size_t)(c0 + ty + j * 8) * R + r0 + tx] = t[tx][ty + j * 8];
}

// V [bh][s][64] f16 -> Vt [bh][64][s] f16.  64x64 tiles, coalesced both sides.
__global__ void vtrans(const unsigned short* __restrict__ V, unsigned short* __restrict__ Vt) {
    __shared__ unsigned short t[64 * 65];
    const int bid = blockIdx.x;
    const int bh  = bid >> 5;
    const int s0  = (bid & 31) * 64;
    const int tid = threadIdx.x;
    const unsigned short* src = V  + (size_t)bh * S_ * DH_ + (size_t)s0 * DH_;
    unsigned short*       dst = Vt + (size_t)bh * DH_ * S_ + s0;
#pragma unroll
    for (int p = 0; p < 2; p++) {
        int c = p * 256 + tid;          // 0..511
        int s = c >> 3, dc = c & 7;
        i32x4 v = *(const i32x4*)&src[s * 64 + dc * 8];
        const unsigned short* e = (const unsigned short*)&v;
#pragma unroll
        for (int j = 0; j < 8; j++) t[(dc * 8 + j) * 65 + s] = e[j];
    }
    __syncthreads();
#pragma unroll
    for (int p = 0; p < 2; p++) {
        int c = p * 256 + tid;
        int d = c >> 3, sc = c & 7;
        unsigned short tmp[8];
#pragma unroll
        for (int j = 0; j < 8; j++) tmp[j] = t[d * 65 + sc * 8 + j];
        *(i32x4*)&dst[(size_t)d * S_ + sc * 8] = *(const i32x4*)tmp;
    }
}

// ---------------------------------------------------------------------------
// GEMM1: QKV projection. C[M][2304] = A[M][768] * Bt[2304][768]^T + bias.
// Tile 128x96, BK=32 -> grid 24x32 = 768 blocks = exactly 3/CU (balanced).
// 256 thr, 4 waves 2x2 (wave tile 64x48, acc 4x3). global_load_lds staging.
// Epilogue scatters Q/K natural bf16 (K scaled) + V natural fp16.
__global__ __launch_bounds__(256) void gemm_qkv(
    const unsigned short* __restrict__ A,
    const unsigned short* __restrict__ Bt,
    const float* __restrict__ bias,
    unsigned short* __restrict__ QK,
    unsigned short* __restrict__ Vnat)
{
    __shared__ __align__(16) short Al[128 * 32];   // 8 KB
    __shared__ __align__(16) short Bl[96 * 32];    // 6 KB

    const int tid  = threadIdx.x;
    const int w    = tid >> 6;
    const int lane = tid & 63;
    const int r    = lane & 15;
    const int quad = lane >> 4;
    const int m0   = blockIdx.y * 128;
    const int n0   = blockIdx.x * 96;
    const int wm   = (w & 1) * 64;
    const int wn   = (w >> 1) * 48;
    const int K    = D_;

    f32x4 acc[4][3];
#pragma unroll
    for (int i = 0; i < 4; i++)
#pragma unroll
        for (int j = 0; j < 3; j++) acc[i][j] = f32x4{0.f, 0.f, 0.f, 0.f};

    // A: 512 chunks (2/thread); B: 384 chunks (1/thread + waves 0,1 one more)
    const int c0 = tid, c1 = tid + 256, cb1 = tid + 256;   // cb1 only if w<2
    const size_t ga0 = (size_t)(m0 + (c0 >> 2)) * K + (c0 & 3) * 8;
    const size_t ga1 = (size_t)(m0 + (c1 >> 2)) * K + (c1 & 3) * 8;
    const size_t gb0 = (size_t)(n0 + (c0 >> 2)) * K + (c0 & 3) * 8;
    const size_t gb1 = (size_t)(n0 + (cb1 >> 2)) * K + (cb1 & 3) * 8;
    short* lA0 = &Al[(0 * 256 + w * 64) * 8];   // wave-uniform bases
    short* lA1 = &Al[(1 * 256 + w * 64) * 8];
    short* lB0 = &Bl[(0 * 256 + w * 64) * 8];
    short* lB1 = &Bl[(1 * 256 + w * 64) * 8];   // only waves 0,1

    for (int k0 = 0; k0 < K; k0 += 32) {
        __syncthreads();
        async_copy16(A  + ga0 + k0, lA0);
        async_copy16(A  + ga1 + k0, lA1);
        async_copy16(Bt + gb0 + k0, lB0);
        if (w < 2) async_copy16(Bt + gb1 + k0, lB1);
        __syncthreads();

        bf16x8 af[4], bf[3];
#pragma unroll
        for (int mi = 0; mi < 4; mi++)
            af[mi] = *(const bf16x8*)&Al[(wm + mi * 16 + r) * 32 + quad * 8];
#pragma unroll
        for (int ni = 0; ni < 3; ni++)
            bf[ni] = *(const bf16x8*)&Bl[(wn + ni * 16 + r) * 32 + quad * 8];
#pragma unroll
        for (int mi = 0; mi < 4; mi++)
#pragma unroll
            for (int ni = 0; ni < 3; ni++)
                acc[mi][ni] = __builtin_amdgcn_mfma_f32_16x16x32_bf16(
                    af[mi], bf[ni], acc[mi][ni], 0, 0, 0);
    }

    // Epilogue. C/D: col = lane&15 (+16*ni), row = quad*4 + reg (+16*mi)
    const size_t one = (size_t)B_ * H_ * S_ * DH_;
#pragma unroll
    for (int ni = 0; ni < 3; ni++) {
        int col  = n0 + wn + ni * 16 + r;        // 0..2303 (tiles never straddle parts)
        float bv = bias[col];
        int part = col / 768;                    // 0=q 1=k 2=v
        int cc   = col - part * 768;
        int h    = cc >> 6;
        int d    = cc & 63;
        float scl = (part == 1) ? KSCALE : 1.0f;
        unsigned short* dst = (part == 2) ? Vnat : (QK + (size_t)part * one);
#pragma unroll
        for (int mi = 0; mi < 4; mi++) {
#pragma unroll
            for (int i = 0; i < 4; i++) {
                int row = m0 + wm + mi * 16 + quad * 4 + i;  // = b*S + s
                int b   = row >> 11;
                int s   = row & 2047;
                float v = (acc[mi][ni][i] + bv) * scl;
                unsigned short bits;
                if (part == 2) {                 // V -> fp16 (PV runs f16)
                    union { _Float16 h; unsigned short s; } cv;
                    cv.h = (_Float16)v;
                    bits = cv.s;
                } else {
                    bits = f2bf(v);
                }
                dst[(((size_t)(b * H_ + h)) * S_ + s) * DH_ + d] = bits;
            }
        }
    }
}

// ---------------------------------------------------------------------------
// GEMM2: output projection. C[M][768] = A[M][768] * Bt[768][768]^T + bias, fp32.
// Tile 64x64, BK=32 -> grid 12x64 = 768 blocks = exactly 3/CU (vs 192 before).
// 256 thr, 4 waves 2x2 (wave tile 32x32, acc 2x2). 8 KB LDS.
__global__ __launch_bounds__(256) void gemm_out(
    const unsigned short* __restrict__ A,
    const unsigned short* __restrict__ Bt,
    const float* __restrict__ bias,
    float* __restrict__ Cf)
{
    __shared__ __align__(16) short Al[64 * 32];    // 4 KB
    __shared__ __align__(16) short Bl[64 * 32];    // 4 KB

    const int tid  = threadIdx.x;
    const int w    = tid >> 6;
    const int lane = tid & 63;
    const int r    = lane & 15;
    const int quad = lane >> 4;
    const int m0   = blockIdx.y * 64;
    const int n0   = blockIdx.x * 64;
    const int wm   = (w & 1) * 32;
    const int wn   = (w >> 1) * 32;
    const int K    = D_;
    const int N    = D_;

    f32x4 acc[2][2];
#pragma unroll
    for (int i = 0; i < 2; i++)
#pragma unroll
        for (int j = 0; j < 2; j++) acc[i][j] = f32x4{0.f, 0.f, 0.f, 0.f};

    // A,B: 256 chunks each -> 1 chunk/thread
    const size_t ga = (size_t)(m0 + (tid >> 2)) * K + (tid & 3) * 8;
    const size_t gb = (size_t)(n0 + (tid >> 2)) * K + (tid & 3) * 8;
    short* lA = &Al[(w * 64) * 8];   // wave-uniform
    short* lB = &Bl[(w * 64) * 8];

    for (int k0 = 0; k0 < K; k0 += 32) {
        __syncthreads();
        async_copy16(A  + ga + k0, lA);
        async_copy16(Bt + gb + k0, lB);
        __syncthreads();

        bf16x8 af[2], bf[2];
#pragma unroll
        for (int mi = 0; mi < 2; mi++)
            af[mi] = *(const bf16x8*)&Al[(wm + mi * 16 + r) * 32 + quad * 8];
#pragma unroll
        for (int ni = 0; ni < 2; ni++)
            bf[ni] = *(const bf16x8*)&Bl[(wn + ni * 16 + r) * 32 + quad * 8];
#pragma unroll
        for (int mi = 0; mi < 2; mi++)
#pragma unroll
            for (int ni = 0; ni < 2; ni++)
                acc[mi][ni] = __builtin_amdgcn_mfma_f32_16x16x32_bf16(
                    af[mi], bf[ni], acc[mi][ni], 0, 0, 0);
    }

#pragma unroll
    for (int ni = 0; ni < 2; ni++) {
        int col  = n0 + wn + ni * 16 + r;
        float bv = bias[col];
#pragma unroll
        for (int mi = 0; mi < 2; mi++) {
#pragma unroll
            for (int i = 0; i < 4; i++) {
                int row = m0 + wm + mi * 16 + quad * 4 + i;
                Cf[(size_t)row * N + col] = acc[mi][ni][i] + bv;
            }
        }
    }
}

// ---------------------------------------------------------------------------
// Flash attention v6: S^T scheme + split-K (x2).
// No max-subtraction softmax combines linearly across key ranges:
//   O = (O0 + O1) / (l0 + l1).  Each block handles 16 of 32 kt-iters.
// Grid = 24 * 16 * 2 = 768 = exactly 3 blocks/CU (balanced, 12 waves/CU).
// Partials: Onum f16 [half][bh][s][64], l f32 [half][bh][s].
// Q,K: bf16 [B*H][S][64] (K pre-scaled). Vt: FP16 [B*H][64][S].
__global__ __launch_bounds__(256) void attn_kernel(
    const unsigned short* __restrict__ Q,
    const unsigned short* __restrict__ K,
    const unsigned short* __restrict__ Vt,
    unsigned short* __restrict__ On0,
    unsigned short* __restrict__ On1,
    float* __restrict__ lbuf)
{
    __shared__ __align__(16) short Kl[64 * 64];      // [key][dh], chunk^=(row&7)
    __shared__ __align__(16) short Vl[64 * 64];      // [dh][key], chunk^=(row&7)

    const int tid  = threadIdx.x;
    const int w    = tid >> 6;
    const int lane = tid & 63;
    const int r    = lane & 15;
    const int quad = lane >> 4;
    const int xk   = r & 7;
    const int bid  = blockIdx.x;
    const int bh   = bid % 24;            // head-major -> L2 locality
    const int t2   = bid / 24;            // 0..31
    const int qb   = t2 & 15;
    const int half = t2 >> 4;
    const size_t baseQK = (size_t)bh * S_ * DH_;
    const size_t baseV  = (size_t)bh * DH_ * S_;
    const int q0   = qb * 128;
    const int kt0  = half * 16;

    // Q fragments (B-operand of S^T: B[k=quad*8+j][n=r] = Q[q=r][d])
    bf16x8 qf[2][2];
#pragma unroll
    for (int qt = 0; qt < 2; qt++) {
        const unsigned short* qp =
            Q + baseQK + (size_t)(q0 + w * 32 + qt * 16 + r) * DH_ + quad * 8;
        qf[qt][0] = *(const bf16x8*)(qp);
        qf[qt][1] = *(const bf16x8*)(qp + 32);
    }

    f32x4 o[2][4];
    f32x4 lacc[2];
#pragma unroll
    for (int qt = 0; qt < 2; qt++) {
        lacc[qt] = f32x4{0.f, 0.f, 0.f, 0.f};
#pragma unroll
        for (int nb = 0; nb < 4; nb++) o[qt][nb] = f32x4{0.f, 0.f, 0.f, 0.f};
    }

    const f16x4 ONES = {(_Float16)1.f, (_Float16)1.f, (_Float16)1.f, (_Float16)1.f};

    // staging: chunk c = p*256 + tid (p=0,1); srow = c>>3 (0..63), schk = c&7
    const int srw = tid >> 3, schk = tid & 7;
    const unsigned short* kg = K  + baseQK + (size_t)kt0 * 4096 + tid * 8;
    const unsigned short* vg = Vt + baseV + (size_t)kt0 * 64 + (size_t)srw * S_ + schk * 8;
    const int lb = srw * 64 + (schk ^ (srw & 7)) * 8;

    i32x4 kreg[2], vreg[2];
    kreg[0] = *(const i32x4*)(kg);
    kreg[1] = *(const i32x4*)(kg + 2048);
    vreg[0] = *(const i32x4*)(vg);
    vreg[1] = *(const i32x4*)(vg + 32 * S_);

    for (int it = 0; it < 16; it++) {
        __syncthreads();
        *(i32x4*)&Kl[lb]        = kreg[0];
        *(i32x4*)&Kl[lb + 2048] = kreg[1];
        *(i32x4*)&Vl[lb]        = vreg[0];
        *(i32x4*)&Vl[lb + 2048] = vreg[1];
        __syncthreads();

        if (it != 15) {
            const unsigned short* kn = kg + (it + 1) * 4096;
            const unsigned short* vn = vg + (it + 1) * 64;
            kreg[0] = *(const i32x4*)(kn);
            kreg[1] = *(const i32x4*)(kn + 2048);
            vreg[0] = *(const i32x4*)(vn);
            vreg[1] = *(const i32x4*)(vn + 32 * S_);
        }

        // S^T = K Q^T  (exp2 domain; KSCALE folded into K)
        f32x4 sa[2][4];
#pragma unroll
        for (int qt = 0; qt < 2; qt++)
#pragma unroll
            for (int kb = 0; kb < 4; kb++) sa[qt][kb] = f32x4{0.f, 0.f, 0.f, 0.f};
#pragma unroll
        for (int t = 0; t < 2; t++)
#pragma unroll
            for (int kb = 0; kb < 4; kb++) {
                bf16x8 kf = *(const bf16x8*)&Kl[(kb * 16 + r) * 64 + ((t * 4 + quad) ^ xk) * 8];
#pragma unroll
                for (int qt = 0; qt < 2; qt++)
                    sa[qt][kb] = __builtin_amdgcn_mfma_f32_16x16x32_bf16(
                        kf, qf[qt][t], sa[qt][kb], 0, 0, 0);
            }

        // p = exp2(s) -> f16 A-frags (layout already matches; cvt_pkrtz = RTZ)
        f16x4 pf[2][4];
#pragma unroll
        for (int qt = 0; qt < 2; qt++)
#pragma unroll
            for (int kb = 0; kb < 4; kb++) {
                float p0 = __builtin_amdgcn_exp2f(sa[qt][kb][0]);
                float p1 = __builtin_amdgcn_exp2f(sa[qt][kb][1]);
                float p2 = __builtin_amdgcn_exp2f(sa[qt][kb][2]);
                float p3 = __builtin_amdgcn_exp2f(sa[qt][kb][3]);
                union { f16x4 v; h16x2 h[2]; } u;
                u.h[0] = __builtin_amdgcn_cvt_pkrtz(p0, p1);
                u.h[1] = __builtin_amdgcn_cvt_pkrtz(p2, p3);
                pf[qt][kb] = u.v;
            }

        // O += P V  and  l += P 1   (fp16 MFMA, K=16 per kb)
#pragma unroll
        for (int kb = 0; kb < 4; kb++) {
#pragma unroll
            for (int nb = 0; nb < 4; nb++) {
                f16x4 vf = *(const f16x4*)&Vl[(nb * 16 + r) * 64 +
                                              ((kb * 2 + (quad >> 1)) ^ xk) * 8 + (quad & 1) * 4];
#pragma unroll
                for (int qt = 0; qt < 2; qt++)
                    o[qt][nb] = __builtin_amdgcn_mfma_f32_16x16x16f16(
                        pf[qt][kb], vf, o[qt][nb], 0, 0, 0);
            }
#pragma unroll
            for (int qt = 0; qt < 2; qt++)
                lacc[qt] = __builtin_amdgcn_mfma_f32_16x16x16f16(
                    pf[qt][kb], ONES, lacc[qt], 0, 0, 0);
        }
    }

    // epilogue: store UN-normalized partials (f16) + l (f32)
    unsigned short* Ob = half ? On1 : On0;
#pragma unroll
    for (int qt = 0; qt < 2; qt++)
#pragma unroll
        for (int i = 0; i < 4; i++) {
            int s = q0 + w * 32 + qt * 16 + quad * 4 + i;
            size_t row = (size_t)bh * S_ + s;
            if (r == 0) lbuf[half * (24 * S_) + row] = lacc[qt][i];
#pragma unroll
            for (int nb = 0; nb < 4; nb++) {
                union { _Float16 h; unsigned short u; } cv;
                cv.h = (_Float16)o[qt][nb][i];
                Ob[row * 64 + nb * 16 + r] = cv.u;
            }
        }
}

// Combine split-K partials: out = (O0+O1)/(l0+l1), bf16 [B][S][D] heads merged.
__global__ void combine_attn(const unsigned short* __restrict__ On0,
                             const unsigned short* __restrict__ On1,
                             const float* __restrict__ lbuf,
                             unsigned short* __restrict__ Out)
{
    int g   = blockIdx.x * 256 + threadIdx.x;   // 0 .. 393215
    int hd8 = g % 96;                           // 12 heads * 8 chunks
    int bs  = g / 96;                           // b*2048 + s
    int h   = hd8 >> 3;
    int d8  = (hd8 & 7) * 8;
    size_t row = ((size_t)((bs >> 11) * H_ + h)) * S_ + (bs & 2047);
    float inv = 1.0f / (lbuf[row] + lbuf[24 * S_ + row]);
    i32x4 a = *(const i32x4*)&On0[row * 64 + d8];
    i32x4 c = *(const i32x4*)&On1[row * 64 + d8];
    const _Float16* fa = (const _Float16*)&a;
    const _Float16* fc = (const _Float16*)&c;
    unsigned short tmp[8];
#pragma unroll
    for (int j = 0; j < 8; j++)
        tmp[j] = f2bf(((float)fa[j] + (float)fc[j]) * inv);
    *(i32x4*)&Out[(size_t)bs * D_ + h * 64 + d8] = *(const i32x4*)tmp;
}

// ---------------------------------------------------------------------------
extern "C" void kernel_launch(void* const* d_in, const int* in_sizes, int n_in,
                              void* d_out, int out_size, void* d_ws, size_t ws_size,
                              hipStream_t stream) {
    const float* x     = (const float*)d_in[0];
    const float* w_in  = (const float*)d_in[1];
    const float* b_in  = (const float*)d_in[2];
    const float* w_out = (const float*)d_in[3];
    const float* b_out = (const float*)d_in[4];
    float* out = (float*)d_out;
    char* ws = (char*)d_ws;

    // workspace layout (bytes), total 36.2 MB:
    //   [0,        6291456)  xb (x bf16)        -> reused as Onum half0 (f16) by attn
    //   [6291456,  9830400)  winT               -> reused as lbuf (f32, 393KB) by attn
    //   [9830400, 11010048)  woutT              (live until gemm2)
    //   [11010048,17301504)  Q  (bf16)          -> reused as attn output (bf16) by combine
    //   [17301504,23592960)  K  (bf16, scaled)
    //   [23592960,29884416)  Vt (fp16)
    //   [29884416,36175872)  tmpV (V natural)   -> reused as Onum half1 (f16) by attn
    unsigned short* xb    = (unsigned short*)(ws);
    unsigned short* winT  = (unsigned short*)(ws + 6291456);
    unsigned short* woutT = (unsigned short*)(ws + 9830400);
    unsigned short* QKV   = (unsigned short*)(ws + 11010048);
    unsigned short* tmpV  = (unsigned short*)(ws + 29884416);

    const size_t one = (size_t)B_ * H_ * S_ * DH_;
    unsigned short* Vtbuf = QKV + 2 * one;
    unsigned short* On0   = xb;                       // dead after gemm1
    unsigned short* On1   = tmpV;                     // dead after vtrans
    float*          lbuf  = (float*)winT;             // dead after gemm1
    unsigned short* attnO = QKV;                      // Q slot, dead after attn

    cvt_bf16<<<3072, 256, 0, stream>>>(x, xb, (M_ * D_) / 4);
    transpose_bf16<<<dim3(N3_ / 32, D_ / 32), dim3(32, 8), 0, stream>>>(w_in, winT, D_, N3_);
    transpose_bf16<<<dim3(D_ / 32, D_ / 32), dim3(32, 8), 0, stream>>>(w_out, woutT, D_, D_);

    gemm_qkv<<<dim3(N3_ / 96, M_ / 128), 256, 0, stream>>>(
        xb, winT, b_in, QKV, tmpV);

    vtrans<<<24 * 32, 256, 0, stream>>>(tmpV, Vtbuf);

    attn_kernel<<<24 * 16 * 2, 256, 0, stream>>>(
        QKV, QKV + one, Vtbuf, On0, On1, lbuf);

    combine_attn<<<1536, 256, 0, stream>>>(On0, On1, lbuf, attnO);

    gemm_out<<<dim3(D_ / 64, M_ / 64), 256, 0, stream>>>(
        attnO, woutT, b_out, out);
}

// Round 11
// 158.888 us; speedup vs baseline: 1.1640x; 1.0517x over previous
//
#include <hip/hip_runtime.h>
#include <stdint.h>

// Problem constants
#define B_   2
#define S_   2048
#define D_   768
#define H_   12
#define DH_  64
#define N3_  2304   // 3*D
#define M_   4096   // B*S

typedef __attribute__((ext_vector_type(8))) short    bf16x8;
typedef __attribute__((ext_vector_type(4))) float    f32x4;
typedef __attribute__((ext_vector_type(4))) int      i32x4;
typedef __attribute__((ext_vector_type(4))) unsigned short u16x4;
typedef _Float16 f16x4 __attribute__((ext_vector_type(4)));
typedef __fp16   h16x2 __attribute__((ext_vector_type(2)));   // cvt_pkrtz result type

// fold 1/sqrt(dh) * log2(e) into K at write time -> scores exit MFMA in exp2 domain
#define KSCALE 0.18033688011112042f

__device__ inline unsigned short f2bf(float f) {
    union { float f; unsigned u; } v; v.f = f;
    unsigned r = v.u + 0x7FFFu + ((v.u >> 16) & 1u);   // RNE
    return (unsigned short)(r >> 16);
}

// async 16B global -> LDS (DMA; LDS dest = wave-uniform base + lane*16)
__device__ inline void async_copy16(const void* g, void* l) {
    __builtin_amdgcn_global_load_lds((const __attribute__((address_space(1))) void*)g,
                                     (__attribute__((address_space(3))) void*)l, 16, 0, 0);
}

// ---------------------------------------------------------------------------
// Fused prep: x->bf16 (blocks 0..3071), w_in transpose (3072..4799),
// w_out transpose (4800..5375). Branch is block-uniform.
__global__ __launch_bounds__(256) void prep_all(
    const float* __restrict__ x, const float* __restrict__ w_in,
    const float* __restrict__ w_out,
    unsigned short* __restrict__ xb, unsigned short* __restrict__ winT,
    unsigned short* __restrict__ woutT)
{
    __shared__ unsigned short t[32][33];
    const int gid = blockIdx.x, tid = threadIdx.x;
    if (gid < 3072) {                      // cvt: 3072*256*4 = M*D elements
        int i = gid * 256 + tid;
        f32x4 v = *(const f32x4*)(x + (size_t)i * 4);
        u16x4 o;
        o.x = f2bf(v.x); o.y = f2bf(v.y); o.z = f2bf(v.z); o.w = f2bf(v.w);
        *(u16x4*)(xb + (size_t)i * 4) = o;
        return;
    }
    const float* src; unsigned short* dst; int R, C, bx, by;
    if (gid < 4800) { int b = gid - 3072; src = w_in;  dst = winT;  R = D_; C = N3_; bx = b % 72; by = b / 72; }
    else            { int b = gid - 4800; src = w_out; dst = woutT; R = D_; C = D_;  bx = b % 24; by = b / 24; }
    int c0 = bx * 32, r0 = by * 32, tx = tid & 31, ty = tid >> 5;
#pragma unroll
    for (int j = 0; j < 4; j++)
        t[ty + j * 8][tx] = f2bf(src[(size_t)(r0 + ty + j * 8) * C + c0 + tx]);
    __syncthreads();
#pragma unroll
    for (int j = 0; j < 4; j++)
        dst[(size_t)(c0 + ty + j * 8) * R + r0 + tx] = t[tx][ty + j * 8];
}

// ---------------------------------------------------------------------------
// GEMM1: QKV projection. C[M][2304] = A[M][768] * Bt[2304][768]^T + bias.
// Tile 128x96, BK=32 -> grid 24x32 = 768 blocks = exactly 3/CU (balanced).
// Epilogue: Q/K natural bf16 (K scaled by KSCALE); V written DIRECTLY as
// transposed fp16 [bh][d][S] via 8B packs (4 consecutive s per lane-reg group)
// -> vtrans kernel and its 19MB round-trip eliminated.
__global__ __launch_bounds__(256) void gemm_qkv(
    const unsigned short* __restrict__ A,
    const unsigned short* __restrict__ Bt,
    const float* __restrict__ bias,
    unsigned short* __restrict__ QK,
    unsigned short* __restrict__ Vt)
{
    __shared__ __align__(16) short Al[128 * 32];   // 8 KB
    __shared__ __align__(16) short Bl[96 * 32];    // 6 KB

    const int tid  = threadIdx.x;
    const int w    = tid >> 6;
    const int lane = tid & 63;
    const int r    = lane & 15;
    const int quad = lane >> 4;
    const int m0   = blockIdx.y * 128;
    const int n0   = blockIdx.x * 96;
    const int wm   = (w & 1) * 64;
    const int wn   = (w >> 1) * 48;
    const int K    = D_;

    f32x4 acc[4][3];
#pragma unroll
    for (int i = 0; i < 4; i++)
#pragma unroll
        for (int j = 0; j < 3; j++) acc[i][j] = f32x4{0.f, 0.f, 0.f, 0.f};

    // A: 512 chunks (2/thread); B: 384 chunks (1/thread + waves 0,1 one more)
    const int c0 = tid, c1 = tid + 256;
    const size_t ga0 = (size_t)(m0 + (c0 >> 2)) * K + (c0 & 3) * 8;
    const size_t ga1 = (size_t)(m0 + (c1 >> 2)) * K + (c1 & 3) * 8;
    const size_t gb0 = (size_t)(n0 + (c0 >> 2)) * K + (c0 & 3) * 8;
    const size_t gb1 = (size_t)(n0 + (c1 >> 2)) * K + (c1 & 3) * 8;
    short* lA0 = &Al[(0 * 256 + w * 64) * 8];   // wave-uniform bases
    short* lA1 = &Al[(1 * 256 + w * 64) * 8];
    short* lB0 = &Bl[(0 * 256 + w * 64) * 8];
    short* lB1 = &Bl[(1 * 256 + w * 64) * 8];   // only waves 0,1

    for (int k0 = 0; k0 < K; k0 += 32) {
        __syncthreads();
        async_copy16(A  + ga0 + k0, lA0);
        async_copy16(A  + ga1 + k0, lA1);
        async_copy16(Bt + gb0 + k0, lB0);
        if (w < 2) async_copy16(Bt + gb1 + k0, lB1);
        __syncthreads();

        bf16x8 af[4], bf[3];
#pragma unroll
        for (int mi = 0; mi < 4; mi++)
            af[mi] = *(const bf16x8*)&Al[(wm + mi * 16 + r) * 32 + quad * 8];
#pragma unroll
        for (int ni = 0; ni < 3; ni++)
            bf[ni] = *(const bf16x8*)&Bl[(wn + ni * 16 + r) * 32 + quad * 8];
#pragma unroll
        for (int mi = 0; mi < 4; mi++)
#pragma unroll
            for (int ni = 0; ni < 3; ni++)
                acc[mi][ni] = __builtin_amdgcn_mfma_f32_16x16x32_bf16(
                    af[mi], bf[ni], acc[mi][ni], 0, 0, 0);
    }

    // Epilogue. C/D: col = lane&15 (+16*ni), row = quad*4 + reg (+16*mi)
    const size_t one = (size_t)B_ * H_ * S_ * DH_;
#pragma unroll
    for (int ni = 0; ni < 3; ni++) {
        int col  = n0 + wn + ni * 16 + r;        // 0..2303 (tiles never straddle parts)
        float bv = bias[col];
        int part = col / 768;                    // 0=q 1=k 2=v
        int cc   = col - part * 768;
        int h    = cc >> 6;
        int d    = cc & 63;
        if (part == 2) {
            // V^T direct: rows i=0..3 are consecutive s -> one 8B f16 pack
#pragma unroll
            for (int mi = 0; mi < 4; mi++) {
                int row0 = m0 + wm + mi * 16 + quad * 4;    // i=0; same b for i=0..3
                int b    = row0 >> 11;
                int s0   = row0 & 2047;
                u16x4 pk;
#pragma unroll
                for (int i = 0; i < 4; i++) {
                    union { _Float16 h; unsigned short s; } cv;
                    cv.h = (_Float16)(acc[mi][ni][i] + bv);
                    pk[i] = cv.s;
                }
                *(u16x4*)&Vt[(((size_t)(b * H_ + h)) * DH_ + d) * S_ + s0] = pk;
            }
        } else {
            float scl = (part == 1) ? KSCALE : 1.0f;
            unsigned short* dst = QK + (size_t)part * one;
#pragma unroll
            for (int mi = 0; mi < 4; mi++) {
#pragma unroll
                for (int i = 0; i < 4; i++) {
                    int row = m0 + wm + mi * 16 + quad * 4 + i;  // = b*S + s
                    int b   = row >> 11;
                    int s   = row & 2047;
                    dst[(((size_t)(b * H_ + h)) * S_ + s) * DH_ + d] =
                        f2bf((acc[mi][ni][i] + bv) * scl);
                }
            }
        }
    }
}

// ---------------------------------------------------------------------------
// GEMM2: output projection. C[M][768] = A[M][768] * Bt[768][768]^T + bias, fp32.
// Tile 64x64, BK=32 -> grid 12x64 = 768 blocks = exactly 3/CU.
__global__ __launch_bounds__(256) void gemm_out(
    const unsigned short* __restrict__ A,
    const unsigned short* __restrict__ Bt,
    const float* __restrict__ bias,
    float* __restrict__ Cf)
{
    __shared__ __align__(16) short Al[64 * 32];    // 4 KB
    __shared__ __align__(16) short Bl[64 * 32];    // 4 KB

    const int tid  = threadIdx.x;
    const int w    = tid >> 6;
    const int lane = tid & 63;
    const int r    = lane & 15;
    const int quad = lane >> 4;
    const int m0   = blockIdx.y * 64;
    const int n0   = blockIdx.x * 64;
    const int wm   = (w & 1) * 32;
    const int wn   = (w >> 1) * 32;
    const int K    = D_;
    const int N    = D_;

    f32x4 acc[2][2];
#pragma unroll
    for (int i = 0; i < 2; i++)
#pragma unroll
        for (int j = 0; j < 2; j++) acc[i][j] = f32x4{0.f, 0.f, 0.f, 0.f};

    const size_t ga = (size_t)(m0 + (tid >> 2)) * K + (tid & 3) * 8;
    const size_t gb = (size_t)(n0 + (tid >> 2)) * K + (tid & 3) * 8;
    short* lA = &Al[(w * 64) * 8];   // wave-uniform
    short* lB = &Bl[(w * 64) * 8];

    for (int k0 = 0; k0 < K; k0 += 32) {
        __syncthreads();
        async_copy16(A  + ga + k0, lA);
        async_copy16(Bt + gb + k0, lB);
        __syncthreads();

        bf16x8 af[2], bf[2];
#pragma unroll
        for (int mi = 0; mi < 2; mi++)
            af[mi] = *(const bf16x8*)&Al[(wm + mi * 16 + r) * 32 + quad * 8];
#pragma unroll
        for (int ni = 0; ni < 2; ni++)
            bf[ni] = *(const bf16x8*)&Bl[(wn + ni * 16 + r) * 32 + quad * 8];
#pragma unroll
        for (int mi = 0; mi < 2; mi++)
#pragma unroll
            for (int ni = 0; ni < 2; ni++)
                acc[mi][ni] = __builtin_amdgcn_mfma_f32_16x16x32_bf16(
                    af[mi], bf[ni], acc[mi][ni], 0, 0, 0);
    }

#pragma unroll
    for (int ni = 0; ni < 2; ni++) {
        int col  = n0 + wn + ni * 16 + r;
        float bv = bias[col];
#pragma unroll
        for (int mi = 0; mi < 2; mi++) {
#pragma unroll
            for (int i = 0; i < 4; i++) {
                int row = m0 + wm + mi * 16 + quad * 4 + i;
                Cf[(size_t)row * N + col] = acc[mi][ni][i] + bv;
            }
        }
    }
}

// ---------------------------------------------------------------------------
// Flash attention v6: S^T scheme + split-K (x2).  (unchanged from R10)
__global__ __launch_bounds__(256) void attn_kernel(
    const unsigned short* __restrict__ Q,
    const unsigned short* __restrict__ K,
    const unsigned short* __restrict__ Vt,
    unsigned short* __restrict__ On0,
    unsigned short* __restrict__ On1,
    float* __restrict__ lbuf)
{
    __shared__ __align__(16) short Kl[64 * 64];      // [key][dh], chunk^=(row&7)
    __shared__ __align__(16) short Vl[64 * 64];      // [dh][key], chunk^=(row&7)

    const int tid  = threadIdx.x;
    const int w    = tid >> 6;
    const int lane = tid & 63;
    const int r    = lane & 15;
    const int quad = lane >> 4;
    const int xk   = r & 7;
    const int bid  = blockIdx.x;
    const int bh   = bid % 24;            // head-major -> L2 locality
    const int t2   = bid / 24;            // 0..31
    const int qb   = t2 & 15;
    const int half = t2 >> 4;
    const size_t baseQK = (size_t)bh * S_ * DH_;
    const size_t baseV  = (size_t)bh * DH_ * S_;
    const int q0   = qb * 128;
    const int kt0  = half * 16;

    bf16x8 qf[2][2];
#pragma unroll
    for (int qt = 0; qt < 2; qt++) {
        const unsigned short* qp =
            Q + baseQK + (size_t)(q0 + w * 32 + qt * 16 + r) * DH_ + quad * 8;
        qf[qt][0] = *(const bf16x8*)(qp);
        qf[qt][1] = *(const bf16x8*)(qp + 32);
    }

    f32x4 o[2][4];
    f32x4 lacc[2];
#pragma unroll
    for (int qt = 0; qt < 2; qt++) {
        lacc[qt] = f32x4{0.f, 0.f, 0.f, 0.f};
#pragma unroll
        for (int nb = 0; nb < 4; nb++) o[qt][nb] = f32x4{0.f, 0.f, 0.f, 0.f};
    }

    const f16x4 ONES = {(_Float16)1.f, (_Float16)1.f, (_Float16)1.f, (_Float16)1.f};

    const int srw = tid >> 3, schk = tid & 7;
    const unsigned short* kg = K  + baseQK + (size_t)kt0 * 4096 + tid * 8;
    const unsigned short* vg = Vt + baseV + (size_t)kt0 * 64 + (size_t)srw * S_ + schk * 8;
    const int lb = srw * 64 + (schk ^ (srw & 7)) * 8;

    i32x4 kreg[2], vreg[2];
    kreg[0] = *(const i32x4*)(kg);
    kreg[1] = *(const i32x4*)(kg + 2048);
    vreg[0] = *(const i32x4*)(vg);
    vreg[1] = *(const i32x4*)(vg + 32 * S_);

    for (int it = 0; it < 16; it++) {
        __syncthreads();
        *(i32x4*)&Kl[lb]        = kreg[0];
        *(i32x4*)&Kl[lb + 2048] = kreg[1];
        *(i32x4*)&Vl[lb]        = vreg[0];
        *(i32x4*)&Vl[lb + 2048] = vreg[1];
        __syncthreads();

        if (it != 15) {
            const unsigned short* kn = kg + (it + 1) * 4096;
            const unsigned short* vn = vg + (it + 1) * 64;
            kreg[0] = *(const i32x4*)(kn);
            kreg[1] = *(const i32x4*)(kn + 2048);
            vreg[0] = *(const i32x4*)(vn);
            vreg[1] = *(const i32x4*)(vn + 32 * S_);
        }

        // S^T = K Q^T  (exp2 domain; KSCALE folded into K)
        f32x4 sa[2][4];
#pragma unroll
        for (int qt = 0; qt < 2; qt++)
#pragma unroll
            for (int kb = 0; kb < 4; kb++) sa[qt][kb] = f32x4{0.f, 0.f, 0.f, 0.f};
#pragma unroll
        for (int t = 0; t < 2; t++)
#pragma unroll
            for (int kb = 0; kb < 4; kb++) {
                bf16x8 kf = *(const bf16x8*)&Kl[(kb * 16 + r) * 64 + ((t * 4 + quad) ^ xk) * 8];
#pragma unroll
                for (int qt = 0; qt < 2; qt++)
                    sa[qt][kb] = __builtin_amdgcn_mfma_f32_16x16x32_bf16(
                        kf, qf[qt][t], sa[qt][kb], 0, 0, 0);
            }

        // p = exp2(s) -> f16 A-frags (layout already matches; cvt_pkrtz = RTZ)
        f16x4 pf[2][4];
#pragma unroll
        for (int qt = 0; qt < 2; qt++)
#pragma unroll
            for (int kb = 0; kb < 4; kb++) {
                float p0 = __builtin_amdgcn_exp2f(sa[qt][kb][0]);
                float p1 = __builtin_amdgcn_exp2f(sa[qt][kb][1]);
                float p2 = __builtin_amdgcn_exp2f(sa[qt][kb][2]);
                float p3 = __builtin_amdgcn_exp2f(sa[qt][kb][3]);
                union { f16x4 v; h16x2 h[2]; } u;
                u.h[0] = __builtin_amdgcn_cvt_pkrtz(p0, p1);
                u.h[1] = __builtin_amdgcn_cvt_pkrtz(p2, p3);
                pf[qt][kb] = u.v;
            }

        // O += P V  and  l += P 1   (fp16 MFMA, K=16 per kb)
#pragma unroll
        for (int kb = 0; kb < 4; kb++) {
#pragma unroll
            for (int nb = 0; nb < 4; nb++) {
                f16x4 vf = *(const f16x4*)&Vl[(nb * 16 + r) * 64 +
                                              ((kb * 2 + (quad >> 1)) ^ xk) * 8 + (quad & 1) * 4];
#pragma unroll
                for (int qt = 0; qt < 2; qt++)
                    o[qt][nb] = __builtin_amdgcn_mfma_f32_16x16x16f16(
                        pf[qt][kb], vf, o[qt][nb], 0, 0, 0);
            }
#pragma unroll
            for (int qt = 0; qt < 2; qt++)
                lacc[qt] = __builtin_amdgcn_mfma_f32_16x16x16f16(
                    pf[qt][kb], ONES, lacc[qt], 0, 0, 0);
        }
    }

    // epilogue: store UN-normalized partials (f16) + l (f32)
    unsigned short* Ob = half ? On1 : On0;
#pragma unroll
    for (int qt = 0; qt < 2; qt++)
#pragma unroll
        for (int i = 0; i < 4; i++) {
            int s = q0 + w * 32 + qt * 16 + quad * 4 + i;
            size_t row = (size_t)bh * S_ + s;
            if (r == 0) lbuf[half * (24 * S_) + row] = lacc[qt][i];
#pragma unroll
            for (int nb = 0; nb < 4; nb++) {
                union { _Float16 h; unsigned short u; } cv;
                cv.h = (_Float16)o[qt][nb][i];
                Ob[row * 64 + nb * 16 + r] = cv.u;
            }
        }
}

// Combine split-K partials: out = (O0+O1)/(l0+l1), bf16 [B][S][D] heads merged.
__global__ void combine_attn(const unsigned short* __restrict__ On0,
                             const unsigned short* __restrict__ On1,
                             const float* __restrict__ lbuf,
                             unsigned short* __restrict__ Out)
{
    int g   = blockIdx.x * 256 + threadIdx.x;   // 0 .. 393215
    int hd8 = g % 96;                           // 12 heads * 8 chunks
    int bs  = g / 96;                           // b*2048 + s
    int h   = hd8 >> 3;
    int d8  = (hd8 & 7) * 8;
    size_t row = ((size_t)((bs >> 11) * H_ + h)) * S_ + (bs & 2047);
    float inv = 1.0f / (lbuf[row] + lbuf[24 * S_ + row]);
    i32x4 a = *(const i32x4*)&On0[row * 64 + d8];
    i32x4 c = *(const i32x4*)&On1[row * 64 + d8];
    const _Float16* fa = (const _Float16*)&a;
    const _Float16* fc = (const _Float16*)&c;
    unsigned short tmp[8];
#pragma unroll
    for (int j = 0; j < 8; j++)
        tmp[j] = f2bf(((float)fa[j] + (float)fc[j]) * inv);
    *(i32x4*)&Out[(size_t)bs * D_ + h * 64 + d8] = *(const i32x4*)tmp;
}

// ---------------------------------------------------------------------------
extern "C" void kernel_launch(void* const* d_in, const int* in_sizes, int n_in,
                              void* d_out, int out_size, void* d_ws, size_t ws_size,
                              hipStream_t stream) {
    const float* x     = (const float*)d_in[0];
    const float* w_in  = (const float*)d_in[1];
    const float* b_in  = (const float*)d_in[2];
    const float* w_out = (const float*)d_in[3];
    const float* b_out = (const float*)d_in[4];
    float* out = (float*)d_out;
    char* ws = (char*)d_ws;

    // workspace layout (bytes), total 36.2 MB:
    //   [0,        6291456)  xb (x bf16)        -> reused as Onum half0 (f16) by attn
    //   [6291456,  9830400)  winT               -> reused as lbuf (f32, 393KB) by attn
    //   [9830400, 11010048)  woutT              (live until gemm_out)
    //   [11010048,17301504)  Q  (bf16)          -> reused as attn output (bf16) by combine
    //   [17301504,23592960)  K  (bf16, scaled)
    //   [23592960,29884416)  Vt (fp16, written transposed by gemm_qkv)
    //   [29884416,36175872)  Onum half1 (f16)
    unsigned short* xb    = (unsigned short*)(ws);
    unsigned short* winT  = (unsigned short*)(ws + 6291456);
    unsigned short* woutT = (unsigned short*)(ws + 9830400);
    unsigned short* QKV   = (unsigned short*)(ws + 11010048);
    unsigned short* On1   = (unsigned short*)(ws + 29884416);

    const size_t one = (size_t)B_ * H_ * S_ * DH_;
    unsigned short* Vtbuf = QKV + 2 * one;
    unsigned short* On0   = xb;                       // dead after gemm_qkv
    float*          lbuf  = (float*)winT;             // dead after gemm_qkv
    unsigned short* attnO = QKV;                      // Q slot, dead after attn

    prep_all<<<5376, 256, 0, stream>>>(x, w_in, w_out, xb, winT, woutT);

    gemm_qkv<<<dim3(N3_ / 96, M_ / 128), 256, 0, stream>>>(
        xb, winT, b_in, QKV, Vtbuf);

    attn_kernel<<<24 * 16 * 2, 256, 0, stream>>>(
        QKV, QKV + one, Vtbuf, On0, On1, lbuf);

    combine_attn<<<1536, 256, 0, stream>>>(On0, On1, lbuf, attnO);

    gemm_out<<<dim3(D_ / 64, M_ / 64), 256, 0, stream>>>(
        attnO, woutT, b_out, out);
}